// Round 8
// baseline (264.381 us; speedup 1.0000x reference)
//
#include <hip/hip_runtime.h>

#define D 128
typedef unsigned int uint;
typedef unsigned short ushort;
typedef __attribute__((ext_vector_type(8))) __bf16 bf16x8;
typedef __attribute__((ext_vector_type(4))) float f32x4;

// round-to-nearest-even f32 -> bf16 (bit trick)
__device__ __forceinline__ ushort f2bf(float f) {
    uint u = __float_as_uint(f);
    u += 0x7fffu + ((u >> 16) & 1u);
    return (ushort)(u >> 16);
}

// ---------------- fused prep: hist + f32->bf16 cvt + W pack ----------------
// blocks [0,HB): histogram of tgt (4 edges/thread, int4 loads)
// blocks [HB,HB+CB): x f32 -> bf16 (8 elems/thread)
// blocks [HB+CB,HB+CB+32): pack W1 (16 blocks) and W2 (16 blocks)

__global__ __launch_bounds__(256) void prep_k(
    const int* __restrict__ tgt, int* __restrict__ cnt, int E, int HB,
    const float* __restrict__ x, ushort* __restrict__ xb, int n8, int CB,
    const float* __restrict__ W1, ushort* __restrict__ wp1,
    const float* __restrict__ W2, ushort* __restrict__ wp2) {
    int b = blockIdx.x;
    if (b < HB) {
        int i = (b * 256 + threadIdx.x) * 4;
        if (i + 3 < E) {
            int4 t = *reinterpret_cast<const int4*>(tgt + i);
            atomicAdd(&cnt[t.x], 1);
            atomicAdd(&cnt[t.y], 1);
            atomicAdd(&cnt[t.z], 1);
            atomicAdd(&cnt[t.w], 1);
        } else {
            for (int j = 0; j < 4; ++j)
                if (i + j < E) atomicAdd(&cnt[tgt[i + j]], 1);
        }
    } else if (b < HB + CB) {
        int i = (b - HB) * 256 + threadIdx.x;  // ushort8 group index
        if (i < n8) {
            const float4* s = reinterpret_cast<const float4*>(x) + (size_t)i * 2;
            float4 a = s[0], c = s[1];
            ushort4 o0, o1;
            o0.x = f2bf(a.x); o0.y = f2bf(a.y); o0.z = f2bf(a.z); o0.w = f2bf(a.w);
            o1.x = f2bf(c.x); o1.y = f2bf(c.y); o1.z = f2bf(c.z); o1.w = f2bf(c.w);
            reinterpret_cast<ushort4*>(xb)[(size_t)i * 2] = o0;
            reinterpret_cast<ushort4*>(xb)[(size_t)i * 2 + 1] = o1;
        }
    } else {
        int pb = b - HB - CB;  // 0..31
        const float* __restrict__ W = (pb < 16) ? W1 : W2;
        ushort* __restrict__ wp = (pb < 16) ? wp1 : wp2;
        int idx = (pb & 15) * 256 + threadIdx.x;  // 0..4095
        int lane = idx & 63;
        int ct = (idx >> 6) & 7;
        int ks = idx >> 9;
        int col = ct * 16 + (lane & 15);
        int k0 = ks * 32 + (lane >> 4) * 8;
        ushort v[8];
#pragma unroll
        for (int e = 0; e < 8; ++e) v[e] = f2bf(W[(size_t)(k0 + e) * D + col]);
        ushort4 lo4; lo4.x = v[0]; lo4.y = v[1]; lo4.z = v[2]; lo4.w = v[3];
        ushort4 hi4; hi4.x = v[4]; hi4.y = v[5]; hi4.z = v[6]; hi4.w = v[7];
        reinterpret_cast<ushort4*>(wp + (size_t)idx * 8)[0] = lo4;
        reinterpret_cast<ushort4*>(wp + (size_t)idx * 8)[1] = hi4;
    }
}

// ---------------- two-level exclusive scan ----------------

__global__ __launch_bounds__(256) void psum_k(const int* __restrict__ cnt,
                                              int* __restrict__ part, int n) {
    int t = threadIdx.x;
    int i = blockIdx.x * 1024 + t * 4;
    int s = 0;
    if (i + 3 < n) {
        int4 v = *reinterpret_cast<const int4*>(cnt + i);
        s = v.x + v.y + v.z + v.w;
    } else {
        for (int j = 0; j < 4; ++j) if (i + j < n) s += cnt[i + j];
    }
#pragma unroll
    for (int off = 1; off < 64; off <<= 1) s += __shfl_xor(s, off);
    __shared__ int ws[4];
    if ((t & 63) == 0) ws[t >> 6] = s;
    __syncthreads();
    if (t == 0) part[blockIdx.x] = ws[0] + ws[1] + ws[2] + ws[3];
}

__global__ void scanp_k(int* __restrict__ part, int* __restrict__ row_ptr,
                        int nb, int n) {
    int t = threadIdx.x;  // blockDim = 64, nb <= 64
    int v = (t < nb) ? part[t] : 0;
    int orig = v;
#pragma unroll
    for (int off = 1; off < 64; off <<= 1) {
        int u = __shfl_up(v, off);
        if (t >= off) v += u;
    }
    if (t < nb) part[t] = v - orig;   // exclusive block offsets
    if (t == 63) row_ptr[n] = v;      // grand total = E
}

// writes row_ptr AND cur (cur starts at the row base; fill bumps it)
__global__ __launch_bounds__(256) void emit_k(const int* __restrict__ cnt,
                                              const int* __restrict__ part,
                                              int* __restrict__ row_ptr,
                                              int* __restrict__ cur, int n) {
    int t = threadIdx.x;
    int i = blockIdx.x * 1024 + t * 4;
    int c[4] = {0, 0, 0, 0};
    if (i + 3 < n) {
        int4 v = *reinterpret_cast<const int4*>(cnt + i);
        c[0] = v.x; c[1] = v.y; c[2] = v.z; c[3] = v.w;
    } else {
        for (int j = 0; j < 4; ++j) if (i + j < n) c[j] = cnt[i + j];
    }
    int s = c[0] + c[1] + c[2] + c[3];
    int v = s;
#pragma unroll
    for (int off = 1; off < 64; off <<= 1) {
        int u = __shfl_up(v, off);
        if ((t & 63) >= off) v += u;
    }
    __shared__ int wtot[4];
    if ((t & 63) == 63) wtot[t >> 6] = v;
    __syncthreads();
    int woff = 0;
    for (int w = 0; w < (t >> 6); ++w) woff += wtot[w];
    int excl = part[blockIdx.x] + woff + (v - s);
    if (i + 3 < n) {
        int4 o;
        o.x = excl;
        o.y = excl + c[0];
        o.z = excl + c[0] + c[1];
        o.w = excl + c[0] + c[1] + c[2];
        *reinterpret_cast<int4*>(row_ptr + i) = o;
        *reinterpret_cast<int4*>(cur + i) = o;
    } else {
        int e = excl;
        for (int j = 0; j < 4; ++j) {
            if (i + j < n) { row_ptr[i + j] = e; cur[i + j] = e; }
            e += c[j];
        }
    }
}

// ---------------- CSR fill: 1 edge/thread (max TLP for atomic latency) ------

__global__ __launch_bounds__(256) void fill_k(const int* __restrict__ src,
                                              const int* __restrict__ tgt,
                                              int* __restrict__ cur,
                                              int* __restrict__ srcs, int E) {
    int i = blockIdx.x * 256 + threadIdx.x;
    if (i < E) {
        int p = atomicAdd(&cur[tgt[i]], 1);
        srcs[p] = src[i];
    }
}

// ---------------- mean aggregation (CSR gather, bf16 rows, f32 accum) -------
// block = 256 threads = 4 waves, one node per wave; 16 edges per iteration
// (4 shfl-broadcast quads). Loads are CONDITIONAL (no wasted row-0 reads for
// masked quads) and issued in a separate phase from accumulation so all 4
// stay in flight; skipped quads contribute zeros (harmless for a sum).

__global__ __launch_bounds__(256) void aggr_k(const ushort* __restrict__ Xb,
                                              const int* __restrict__ srcs,
                                              const int* __restrict__ row_ptr,
                                              ushort* __restrict__ aggr, int N) {
    int node = blockIdx.x * 4 + (threadIdx.x >> 6);
    if (node >= N) return;
    int lane = threadIdx.x & 63;
    int g = lane >> 4, l = lane & 15;
    int lo = row_ptr[node], hi = row_ptr[node + 1];
    float acc[8] = {0.f, 0.f, 0.f, 0.f, 0.f, 0.f, 0.f, 0.f};
    for (int base = lo; base < hi; base += 64) {
        int idx = base + lane;
        int sv = (idx < hi) ? srcs[idx] : -1;
        int cnt = min(64, hi - base);
        for (int e = 0; e < cnt; e += 16) {
            int ss[4];
#pragma unroll
            for (int q = 0; q < 4; ++q) ss[q] = __shfl(sv, e + q * 4 + g);
            uint4 vv[4];
#pragma unroll
            for (int q = 0; q < 4; ++q) {
                vv[q].x = 0; vv[q].y = 0; vv[q].z = 0; vv[q].w = 0;
            }
#pragma unroll
            for (int q = 0; q < 4; ++q)
                if (ss[q] >= 0)
                    vv[q] = *reinterpret_cast<const uint4*>(Xb + (size_t)ss[q] * D + l * 8);
#pragma unroll
            for (int q = 0; q < 4; ++q) {
                acc[0] += __uint_as_float(vv[q].x << 16);
                acc[1] += __uint_as_float(vv[q].x & 0xffff0000u);
                acc[2] += __uint_as_float(vv[q].y << 16);
                acc[3] += __uint_as_float(vv[q].y & 0xffff0000u);
                acc[4] += __uint_as_float(vv[q].z << 16);
                acc[5] += __uint_as_float(vv[q].z & 0xffff0000u);
                acc[6] += __uint_as_float(vv[q].w << 16);
                acc[7] += __uint_as_float(vv[q].w & 0xffff0000u);
            }
        }
    }
#pragma unroll
    for (int j = 0; j < 8; ++j) {
        acc[j] += __shfl_xor(acc[j], 16);
        acc[j] += __shfl_xor(acc[j], 32);
    }
    if (g == 0) {
        float inv = 1.0f / fmaxf((float)(hi - lo), 1.0f);
        ushort4 o0, o1;
        o0.x = f2bf(acc[0] * inv); o0.y = f2bf(acc[1] * inv);
        o0.z = f2bf(acc[2] * inv); o0.w = f2bf(acc[3] * inv);
        o1.x = f2bf(acc[4] * inv); o1.y = f2bf(acc[5] * inv);
        o1.z = f2bf(acc[6] * inv); o1.w = f2bf(acc[7] * inv);
        ushort* dst = aggr + (size_t)node * D + l * 8;
        reinterpret_cast<ushort4*>(dst)[0] = o0;
        reinterpret_cast<ushort4*>(dst)[1] = o1;
    }
}

// ---------------- MFMA concat-GEMM + bias + relu ----------------
// C[n][128] = relu( concat(Xb,Ab)[n][256] @ W + b ),  bf16 inputs, f32 acc.
// Block = 256 thr = 4 waves. Wave w: rows [blk*64+(w&1)*32, +32),
// col tiles ct0=(w>>1)*4 .. +4 (64 cols). 8 k-steps of 32 (4 from Xb, 4 from Ab).

__global__ __launch_bounds__(256) void gemm_k(
    const ushort* __restrict__ Xb, const ushort* __restrict__ Ab,
    const ushort* __restrict__ Wp, const float* __restrict__ bias,
    float* __restrict__ outf, ushort* __restrict__ outb, int n) {
    int lane = threadIdx.x & 63;
    int w = threadIdx.x >> 6;
    int row_base = blockIdx.x * 64 + (w & 1) * 32;
    int ct0 = (w >> 1) * 4;
    int r0 = row_base + (lane & 15);
    int r1 = row_base + 16 + (lane & 15);
    if (r0 > n - 1) r0 = n - 1;
    if (r1 > n - 1) r1 = n - 1;
    int klo = (lane >> 4) * 8;

    f32x4 acc[2][4] = {};
#pragma unroll
    for (int ks = 0; ks < 8; ++ks) {
        const ushort* __restrict__ S = (ks < 4) ? Xb : Ab;
        int koff = (ks & 3) * 32 + klo;
        bf16x8 a0 = *reinterpret_cast<const bf16x8*>(S + (size_t)r0 * D + koff);
        bf16x8 a1 = *reinterpret_cast<const bf16x8*>(S + (size_t)r1 * D + koff);
        const ushort* wb = Wp + ((size_t)(ks * 8 + ct0) * 64 + lane) * 8;
#pragma unroll
        for (int c = 0; c < 4; ++c) {
            bf16x8 b = *reinterpret_cast<const bf16x8*>(wb + (size_t)c * 64 * 8);
            acc[0][c] = __builtin_amdgcn_mfma_f32_16x16x32_bf16(a0, b, acc[0][c], 0, 0, 0);
            acc[1][c] = __builtin_amdgcn_mfma_f32_16x16x32_bf16(a1, b, acc[1][c], 0, 0, 0);
        }
    }

    int cw = lane & 15;
    int rq = lane >> 4;
#pragma unroll
    for (int rt = 0; rt < 2; ++rt) {
#pragma unroll
        for (int c = 0; c < 4; ++c) {
            int col = (ct0 + c) * 16 + cw;
            float bv = bias[col];
#pragma unroll
            for (int r = 0; r < 4; ++r) {
                int node = row_base + rt * 16 + rq * 4 + r;
                if (node < n) {
                    float v = fmaxf(acc[rt][c][r] + bv, 0.f);
                    if (outf) outf[(size_t)node * D + col] = v;
                    if (outb) outb[(size_t)node * D + col] = f2bf(v);
                }
            }
        }
    }
}

extern "C" void kernel_launch(void* const* d_in, const int* in_sizes, int n_in,
                              void* d_out, int out_size, void* d_ws, size_t ws_size,
                              hipStream_t stream) {
    const float* x  = (const float*)d_in[0];
    const int*   ei = (const int*)d_in[1];
    const float* W1 = (const float*)d_in[2];
    const float* b1 = (const float*)d_in[3];
    const float* W2 = (const float*)d_in[4];
    const float* b2 = (const float*)d_in[5];
    float* out = (float*)d_out;

    const int N = in_sizes[0] / D;  // 50000
    const int E = in_sizes[1] / 2;  // 800000
    const int* src = ei;
    const int* tgt = ei + E;

    char* w = (char*)d_ws;
    auto alloc = [&](size_t bytes) -> char* {
        char* p = w;
        w += ((bytes + 255) / 256) * 256;
        return p;
    };
    int*    row_ptr = (int*)alloc((size_t)(N + 1) * 4);
    int*    cnt     = (int*)alloc((size_t)N * 4);
    int*    cur     = (int*)alloc((size_t)N * 4);
    int*    part    = (int*)alloc(64 * 4);
    int*    srcs    = (int*)alloc((size_t)E * 4);
    ushort* xb      = (ushort*)alloc((size_t)N * D * 2);  // x   bf16
    ushort* h1b     = (ushort*)alloc((size_t)N * D * 2);  // h1  bf16
    ushort* ab      = (ushort*)alloc((size_t)N * D * 2);  // aggr bf16 (both layers)
    ushort* wp1     = (ushort*)alloc((size_t)8 * 8 * 64 * 8 * 2);
    ushort* wp2     = (ushort*)alloc((size_t)8 * 8 * 64 * 8 * 2);

    const int NB = (N + 1023) / 1024;        // 49 scan blocks
    const int HB = (E + 1023) / 1024;        // 782 hist blocks (4 edges/thr)
    const int n8 = N * D / 8;                // ushort8 groups in x
    const int CB = (n8 + 255) / 256;         // 3125 cvt blocks

    // cnt must be zero before prep_k's histogram
    hipMemsetAsync(cnt, 0, (size_t)N * sizeof(int), stream);

    // ---- fused prep: hist + cvt + pack (one dispatch) ----
    prep_k<<<HB + CB + 32, 256, 0, stream>>>(tgt, cnt, E, HB,
                                             x, xb, n8, CB,
                                             W1, wp1, W2, wp2);

    // ---- scan + CSR fill ----
    psum_k<<<NB, 256, 0, stream>>>(cnt, part, N);
    scanp_k<<<1, 64, 0, stream>>>(part, row_ptr, NB, N);
    emit_k<<<NB, 256, 0, stream>>>(cnt, part, row_ptr, cur, N);
    fill_k<<<(E + 255) / 256, 256, 0, stream>>>(src, tgt, cur, srcs, E);

    // ---- layer 1 ----
    aggr_k<<<(N + 3) / 4, 256, 0, stream>>>(xb, srcs, row_ptr, ab, N);
    gemm_k<<<(N + 63) / 64, 256, 0, stream>>>(xb, ab, wp1, b1, nullptr, h1b, N);

    // ---- layer 2 ----
    aggr_k<<<(N + 3) / 4, 256, 0, stream>>>(h1b, srcs, row_ptr, ab, N);
    gemm_k<<<(N + 63) / 64, 256, 0, stream>>>(h1b, ab, wp2, b2, out, nullptr, N);
}

// Round 11
// 207.555 us; speedup vs baseline: 1.2738x; 1.2738x over previous
//
#include <hip/hip_runtime.h>

#define D 128
#define NPB 128              // nodes per bucket
#define BSH 7                // log2(NPB)
typedef unsigned int uint;
typedef unsigned short ushort;
typedef __attribute__((ext_vector_type(8))) __bf16 bf16x8;
typedef __attribute__((ext_vector_type(4))) float f32x4;

// round-to-nearest-even f32 -> bf16 (bit trick)
__device__ __forceinline__ ushort f2bf(float f) {
    uint u = __float_as_uint(f);
    u += 0x7fffu + ((u >> 16) & 1u);
    return (ushort)(u >> 16);
}

// ---------------- bucket histogram (LDS-aggregated) ----------------
// 4096 edges/block; bucket = tgt >> BSH.

__global__ __launch_bounds__(256) void bhist_k(const int* __restrict__ tgt,
                                               int* __restrict__ bhist,
                                               int E, int NBKT) {
    __shared__ int lh[512];
    for (int t = threadIdx.x; t < NBKT; t += 256) lh[t] = 0;
    __syncthreads();
    int i0 = blockIdx.x * 4096 + threadIdx.x * 4;
#pragma unroll
    for (int k = 0; k < 4; ++k) {
        int i = i0 + k * 1024;
        if (i + 3 < E) {
            int4 v = *reinterpret_cast<const int4*>(tgt + i);
            atomicAdd(&lh[v.x >> BSH], 1);
            atomicAdd(&lh[v.y >> BSH], 1);
            atomicAdd(&lh[v.z >> BSH], 1);
            atomicAdd(&lh[v.w >> BSH], 1);
        } else {
            for (int j = 0; j < 4; ++j)
                if (i + j < E) atomicAdd(&lh[tgt[i + j] >> BSH], 1);
        }
    }
    __syncthreads();
    for (int t = threadIdx.x; t < NBKT; t += 256)
        if (lh[t]) atomicAdd(&bhist[t], lh[t]);
}

// ---------------- bucket scan (one block, 512 thr >= NBKT) ----------------

__global__ __launch_bounds__(512) void bscan_k(const int* __restrict__ bhist,
                                               int* __restrict__ bbase,
                                               int* __restrict__ bcur,
                                               int* __restrict__ row_ptr,
                                               int NBKT, int N) {
    int t = threadIdx.x;
    int v = (t < NBKT) ? bhist[t] : 0;
    int lane = t & 63, w = t >> 6;
    int inc = v;
#pragma unroll
    for (int off = 1; off < 64; off <<= 1) {
        int u = __shfl_up(inc, off);
        if (lane >= off) inc += u;
    }
    __shared__ int wt[8];
    if (lane == 63) wt[w] = inc;
    __syncthreads();
    int add = 0;
    for (int i = 0; i < w; ++i) add += wt[i];
    int excl = inc - v + add;
    if (t < NBKT) { bbase[t] = excl; bcur[t] = excl; }
    if (t == NBKT - 1) row_ptr[N] = excl + v;  // = E
}

// ---------------- pass A: partition edges into bucket staging --------------
// staging word = (src << BSH) | (tgt & (NPB-1)); 4096 edges/block.

__global__ __launch_bounds__(256) void passA_k(const int* __restrict__ src,
                                               const int* __restrict__ tgt,
                                               int* __restrict__ bcur,
                                               int* __restrict__ staging,
                                               int E, int NBKT) {
    __shared__ int lh[512], lb[512];
    for (int t = threadIdx.x; t < NBKT; t += 256) lh[t] = 0;
    __syncthreads();
    int i0 = blockIdx.x * 4096 + threadIdx.x * 4;
    int sv[16], tv[16], rk[16];
#pragma unroll
    for (int k = 0; k < 4; ++k) {
        int i = i0 + k * 1024;
        if (i + 3 < E) {
            int4 s4 = *reinterpret_cast<const int4*>(src + i);
            int4 t4 = *reinterpret_cast<const int4*>(tgt + i);
            sv[k * 4 + 0] = s4.x; tv[k * 4 + 0] = t4.x;
            sv[k * 4 + 1] = s4.y; tv[k * 4 + 1] = t4.y;
            sv[k * 4 + 2] = s4.z; tv[k * 4 + 2] = t4.z;
            sv[k * 4 + 3] = s4.w; tv[k * 4 + 3] = t4.w;
        } else {
            for (int j = 0; j < 4; ++j) {
                if (i + j < E) { sv[k * 4 + j] = src[i + j]; tv[k * 4 + j] = tgt[i + j]; }
                else tv[k * 4 + j] = -1;
            }
        }
#pragma unroll
        for (int j = 0; j < 4; ++j) {
            int e = k * 4 + j;
            rk[e] = (tv[e] >= 0) ? atomicAdd(&lh[tv[e] >> BSH], 1) : 0;
        }
    }
    __syncthreads();
    for (int t = threadIdx.x; t < NBKT; t += 256)
        lb[t] = lh[t] ? atomicAdd(&bcur[t], lh[t]) : 0;
    __syncthreads();
#pragma unroll
    for (int e = 0; e < 16; ++e) {
        if (tv[e] >= 0) {
            int b = tv[e] >> BSH;
            staging[lb[b] + rk[e]] = (sv[e] << BSH) | (tv[e] & (NPB - 1));
        }
    }
}

// ---------------- pass B: per-bucket CSR finalize --------------------------
// One block per bucket: per-node count -> in-block scan -> row_ptr for the
// bucket's nodes -> place edges into the bucket's contiguous CSR segment.

__global__ __launch_bounds__(256) void passB_k(const int* __restrict__ bbase,
                                               const int* __restrict__ staging,
                                               int* __restrict__ row_ptr,
                                               int* __restrict__ srcs,
                                               int N, int NBKT, int E) {
    int b = blockIdx.x;
    int s = bbase[b];
    int e = (b + 1 < NBKT) ? bbase[b + 1] : E;
    int t = threadIdx.x;
    __shared__ int nh[NPB], nb[NPB];
    __shared__ int w0tot;
    if (t < NPB) nh[t] = 0;
    __syncthreads();
    for (int i = s + t; i < e; i += 256)
        atomicAdd(&nh[staging[i] & (NPB - 1)], 1);
    __syncthreads();
    int v = 0, inc = 0;
    if (t < NPB) {
        v = nh[t];
        inc = v;
        int lane = t & 63;
#pragma unroll
        for (int off = 1; off < 64; off <<= 1) {
            int u = __shfl_up(inc, off);
            if (lane >= off) inc += u;
        }
        if (lane == 63 && t < 64) w0tot = inc;
    }
    __syncthreads();
    if (t < NPB) {
        int excl = inc - v + ((t >= 64) ? w0tot : 0);
        nb[t] = s + excl;
        int node = b * NPB + t;
        if (node < N) row_ptr[node] = s + excl;
        nh[t] = 0;
    }
    __syncthreads();
    for (int i = s + t; i < e; i += 256) {
        int pv = staging[i];
        int tl = pv & (NPB - 1);
        int p = nb[tl] + atomicAdd(&nh[tl], 1);
        srcs[p] = pv >> BSH;
    }
}

// ---------------- fused prep: f32->bf16 cvt + W pack ----------------
// blocks [0,CB): x f32 -> bf16 (8 elems/thread)
// blocks [CB,CB+32): pack W1 (16 blocks) and W2 (16 blocks)

__global__ __launch_bounds__(256) void prep_k(
    const float* __restrict__ x, ushort* __restrict__ xb, int n8, int CB,
    const float* __restrict__ W1, ushort* __restrict__ wp1,
    const float* __restrict__ W2, ushort* __restrict__ wp2) {
    int b = blockIdx.x;
    if (b < CB) {
        int i = b * 256 + threadIdx.x;  // ushort8 group index
        if (i < n8) {
            const float4* s = reinterpret_cast<const float4*>(x) + (size_t)i * 2;
            float4 a = s[0], c = s[1];
            ushort4 o0, o1;
            o0.x = f2bf(a.x); o0.y = f2bf(a.y); o0.z = f2bf(a.z); o0.w = f2bf(a.w);
            o1.x = f2bf(c.x); o1.y = f2bf(c.y); o1.z = f2bf(c.z); o1.w = f2bf(c.w);
            reinterpret_cast<ushort4*>(xb)[(size_t)i * 2] = o0;
            reinterpret_cast<ushort4*>(xb)[(size_t)i * 2 + 1] = o1;
        }
    } else {
        int pb = b - CB;  // 0..31
        const float* __restrict__ W = (pb < 16) ? W1 : W2;
        ushort* __restrict__ wp = (pb < 16) ? wp1 : wp2;
        int idx = (pb & 15) * 256 + threadIdx.x;  // 0..4095
        int lane = idx & 63;
        int ct = (idx >> 6) & 7;
        int ks = idx >> 9;
        int col = ct * 16 + (lane & 15);
        int k0 = ks * 32 + (lane >> 4) * 8;
        ushort v[8];
#pragma unroll
        for (int e = 0; e < 8; ++e) v[e] = f2bf(W[(size_t)(k0 + e) * D + col]);
        ushort4 lo4; lo4.x = v[0]; lo4.y = v[1]; lo4.z = v[2]; lo4.w = v[3];
        ushort4 hi4; hi4.x = v[4]; hi4.y = v[5]; hi4.z = v[6]; hi4.w = v[7];
        reinterpret_cast<ushort4*>(wp + (size_t)idx * 8)[0] = lo4;
        reinterpret_cast<ushort4*>(wp + (size_t)idx * 8)[1] = hi4;
    }
}

// ---------------- mean aggregation (CSR gather, bf16 rows, f32 accum) -------
// block = 256 threads = 4 waves, one node per wave; 16 edges per iteration
// (4 shfl-broadcast quads), conditional loads issued in a separate phase.

__global__ __launch_bounds__(256) void aggr_k(const ushort* __restrict__ Xb,
                                              const int* __restrict__ srcs,
                                              const int* __restrict__ row_ptr,
                                              ushort* __restrict__ aggr, int N) {
    int node = blockIdx.x * 4 + (threadIdx.x >> 6);
    if (node >= N) return;
    int lane = threadIdx.x & 63;
    int g = lane >> 4, l = lane & 15;
    int lo = row_ptr[node], hi = row_ptr[node + 1];
    float acc[8] = {0.f, 0.f, 0.f, 0.f, 0.f, 0.f, 0.f, 0.f};
    for (int base = lo; base < hi; base += 64) {
        int idx = base + lane;
        int sv = (idx < hi) ? srcs[idx] : -1;
        int cnt = min(64, hi - base);
        for (int e = 0; e < cnt; e += 16) {
            int ss[4];
#pragma unroll
            for (int q = 0; q < 4; ++q) ss[q] = __shfl(sv, e + q * 4 + g);
            uint4 vv[4];
#pragma unroll
            for (int q = 0; q < 4; ++q) {
                vv[q].x = 0; vv[q].y = 0; vv[q].z = 0; vv[q].w = 0;
            }
#pragma unroll
            for (int q = 0; q < 4; ++q)
                if (ss[q] >= 0)
                    vv[q] = *reinterpret_cast<const uint4*>(Xb + (size_t)ss[q] * D + l * 8);
#pragma unroll
            for (int q = 0; q < 4; ++q) {
                acc[0] += __uint_as_float(vv[q].x << 16);
                acc[1] += __uint_as_float(vv[q].x & 0xffff0000u);
                acc[2] += __uint_as_float(vv[q].y << 16);
                acc[3] += __uint_as_float(vv[q].y & 0xffff0000u);
                acc[4] += __uint_as_float(vv[q].z << 16);
                acc[5] += __uint_as_float(vv[q].z & 0xffff0000u);
                acc[6] += __uint_as_float(vv[q].w << 16);
                acc[7] += __uint_as_float(vv[q].w & 0xffff0000u);
            }
        }
    }
#pragma unroll
    for (int j = 0; j < 8; ++j) {
        acc[j] += __shfl_xor(acc[j], 16);
        acc[j] += __shfl_xor(acc[j], 32);
    }
    if (g == 0) {
        float inv = 1.0f / fmaxf((float)(hi - lo), 1.0f);
        ushort4 o0, o1;
        o0.x = f2bf(acc[0] * inv); o0.y = f2bf(acc[1] * inv);
        o0.z = f2bf(acc[2] * inv); o0.w = f2bf(acc[3] * inv);
        o1.x = f2bf(acc[4] * inv); o1.y = f2bf(acc[5] * inv);
        o1.z = f2bf(acc[6] * inv); o1.w = f2bf(acc[7] * inv);
        ushort* dst = aggr + (size_t)node * D + l * 8;
        reinterpret_cast<ushort4*>(dst)[0] = o0;
        reinterpret_cast<ushort4*>(dst)[1] = o1;
    }
}

// ---------------- MFMA concat-GEMM + bias + relu ----------------
// C[n][128] = relu( concat(Xb,Ab)[n][256] @ W + b ),  bf16 inputs, f32 acc.

__global__ __launch_bounds__(256) void gemm_k(
    const ushort* __restrict__ Xb, const ushort* __restrict__ Ab,
    const ushort* __restrict__ Wp, const float* __restrict__ bias,
    float* __restrict__ outf, ushort* __restrict__ outb, int n) {
    int lane = threadIdx.x & 63;
    int w = threadIdx.x >> 6;
    int row_base = blockIdx.x * 64 + (w & 1) * 32;
    int ct0 = (w >> 1) * 4;
    int r0 = row_base + (lane & 15);
    int r1 = row_base + 16 + (lane & 15);
    if (r0 > n - 1) r0 = n - 1;
    if (r1 > n - 1) r1 = n - 1;
    int klo = (lane >> 4) * 8;

    f32x4 acc[2][4] = {};
#pragma unroll
    for (int ks = 0; ks < 8; ++ks) {
        const ushort* __restrict__ S = (ks < 4) ? Xb : Ab;
        int koff = (ks & 3) * 32 + klo;
        bf16x8 a0 = *reinterpret_cast<const bf16x8*>(S + (size_t)r0 * D + koff);
        bf16x8 a1 = *reinterpret_cast<const bf16x8*>(S + (size_t)r1 * D + koff);
        const ushort* wb = Wp + ((size_t)(ks * 8 + ct0) * 64 + lane) * 8;
#pragma unroll
        for (int c = 0; c < 4; ++c) {
            bf16x8 b = *reinterpret_cast<const bf16x8*>(wb + (size_t)c * 64 * 8);
            acc[0][c] = __builtin_amdgcn_mfma_f32_16x16x32_bf16(a0, b, acc[0][c], 0, 0, 0);
            acc[1][c] = __builtin_amdgcn_mfma_f32_16x16x32_bf16(a1, b, acc[1][c], 0, 0, 0);
        }
    }

    int cw = lane & 15;
    int rq = lane >> 4;
#pragma unroll
    for (int rt = 0; rt < 2; ++rt) {
#pragma unroll
        for (int c = 0; c < 4; ++c) {
            int col = (ct0 + c) * 16 + cw;
            float bv = bias[col];
#pragma unroll
            for (int r = 0; r < 4; ++r) {
                int node = row_base + rt * 16 + rq * 4 + r;
                if (node < n) {
                    float v = fmaxf(acc[rt][c][r] + bv, 0.f);
                    if (outf) outf[(size_t)node * D + col] = v;
                    if (outb) outb[(size_t)node * D + col] = f2bf(v);
                }
            }
        }
    }
}

extern "C" void kernel_launch(void* const* d_in, const int* in_sizes, int n_in,
                              void* d_out, int out_size, void* d_ws, size_t ws_size,
                              hipStream_t stream) {
    const float* x  = (const float*)d_in[0];
    const int*   ei = (const int*)d_in[1];
    const float* W1 = (const float*)d_in[2];
    const float* b1 = (const float*)d_in[3];
    const float* W2 = (const float*)d_in[4];
    const float* b2 = (const float*)d_in[5];
    float* out = (float*)d_out;

    const int N = in_sizes[0] / D;  // 50000
    const int E = in_sizes[1] / 2;  // 800000
    const int* src = ei;
    const int* tgt = ei + E;

    char* w = (char*)d_ws;
    auto alloc = [&](size_t bytes) -> char* {
        char* p = w;
        w += ((bytes + 255) / 256) * 256;
        return p;
    };
    const int NBKT = (N + NPB - 1) / NPB;    // 391 buckets
    int*    row_ptr = (int*)alloc((size_t)(N + 1) * 4);
    int*    bhist   = (int*)alloc((size_t)NBKT * 4);
    int*    bbase   = (int*)alloc((size_t)NBKT * 4);
    int*    bcur    = (int*)alloc((size_t)NBKT * 4);
    int*    staging = (int*)alloc((size_t)E * 4);
    int*    srcs    = (int*)alloc((size_t)E * 4);
    ushort* xb      = (ushort*)alloc((size_t)N * D * 2);  // x   bf16
    ushort* h1b     = (ushort*)alloc((size_t)N * D * 2);  // h1  bf16
    ushort* ab      = (ushort*)alloc((size_t)N * D * 2);  // aggr bf16 (both layers)
    ushort* wp1     = (ushort*)alloc((size_t)8 * 8 * 64 * 8 * 2);
    ushort* wp2     = (ushort*)alloc((size_t)8 * 8 * 64 * 8 * 2);

    const int EB = (E + 4095) / 4096;        // 196 edge blocks (16 edges/thr)
    const int n8 = N * D / 8;                // ushort8 groups in x
    const int CB = (n8 + 255) / 256;         // 3125 cvt blocks

    // ---- bucketed counting sort -> CSR (row_ptr, srcs) ----
    hipMemsetAsync(bhist, 0, (size_t)NBKT * sizeof(int), stream);
    bhist_k<<<EB, 256, 0, stream>>>(tgt, bhist, E, NBKT);
    prep_k<<<CB + 32, 256, 0, stream>>>(x, xb, n8, CB, W1, wp1, W2, wp2);
    bscan_k<<<1, 512, 0, stream>>>(bhist, bbase, bcur, row_ptr, NBKT, N);
    passA_k<<<EB, 256, 0, stream>>>(src, tgt, bcur, staging, E, NBKT);
    passB_k<<<NBKT, 256, 0, stream>>>(bbase, staging, row_ptr, srcs, N, NBKT, E);

    // ---- layer 1 ----
    aggr_k<<<(N + 3) / 4, 256, 0, stream>>>(xb, srcs, row_ptr, ab, N);
    gemm_k<<<(N + 63) / 64, 256, 0, stream>>>(xb, ab, wp1, b1, nullptr, h1b, N);

    // ---- layer 2 ----
    aggr_k<<<(N + 3) / 4, 256, 0, stream>>>(h1b, srcs, row_ptr, ab, N);
    gemm_k<<<(N + 63) / 64, 256, 0, stream>>>(h1b, ab, wp2, b2, out, nullptr, N);
}